// Round 6
// baseline (367.606 us; speedup 1.0000x reference)
//
#include <hip/hip_runtime.h>

// Problem constants: B=32, L=2, F=65536, D=768
#define BB 32
#define LL 2
#define FF 65536
#define DD 768
#define F4 (FF / 4)        // 16384 groups of 4 f
#define LD (LL * DD)       // 1536
#define LD4 (LD / 4)       // 384
#define D4 (DD / 4)        // 192

#define FT_FLOAT4S ((size_t)F4 * BB)            // 524288 float4 = 8.39 MB
#define FT_BYTES   (FT_FLOAT4S * sizeof(float4))
#define CHUNK_BYTES ((size_t)BB * LD * sizeof(float))  // 196608 B

#define FMA4(A, W, S)                                                          \
    do {                                                                       \
        (A).x = fmaf((W).x, (S), (A).x);                                       \
        (A).y = fmaf((W).y, (S), (A).y);                                       \
        (A).z = fmaf((W).z, (S), (A).z);                                       \
        (A).w = fmaf((W).w, (S), (A).w);                                       \
    } while (0)

// Stage 0: transpose f (B x F) -> fT[g][b] as float4.
__global__ __launch_bounds__(256) void cc_transpose(
    const float4* __restrict__ f4, float4* __restrict__ fT4)
{
    size_t t = (size_t)blockIdx.x * 256 + threadIdx.x;   // 0 .. F4*32-1
    if (t >= FT_FLOAT4S) return;
    int b = (int)(t / F4);
    int g = (int)(t - (size_t)b * F4);
    fT4[(size_t)g * BB + b] = f4[t];
}

// Stage 1: partial GEMM over an F-chunk, depth-2 weight prefetch.
// grid = (6, NF); block = 64 (one wave).  ct: l = ct/3, dt = ct%3 (256 d each).
// partials[c][b][l*768 + dt*256 + lane*4].  chunk4 is EVEN, remainder even >= 2.
__global__ __launch_bounds__(64, 1) void cc_stage1(
    const float4* __restrict__ fT4,     // [F4][32] float4
    const float* __restrict__ weight,   // L x F x D
    float* __restrict__ partials,       // NF x B x LD
    int chunk4)
{
    const int lane = threadIdx.x;
    const int ct   = blockIdx.x;        // 0..5
    const int c    = blockIdx.y;        // chunk
    const int l    = ct / 3;
    const int dt   = ct - l * 3;

    const float4* __restrict__ w4p =
        (const float4*)weight + (size_t)l * FF * D4 + (size_t)dt * 64 + lane;

    int g0 = c * chunk4;
    int g1 = g0 + chunk4;
    if (g1 > F4) g1 = F4;          // remainder is even and >= 2 by construction

    float4 acc[BB];
#pragma unroll
    for (int b = 0; b < BB; ++b) acc[b] = make_float4(0.f, 0.f, 0.f, 0.f);

    // two static weight-row buffers (A = even row, B = odd row)
    float4 a0 = w4p[((size_t)g0 * 4 + 0) * D4];
    float4 a1 = w4p[((size_t)g0 * 4 + 1) * D4];
    float4 a2 = w4p[((size_t)g0 * 4 + 2) * D4];
    float4 a3 = w4p[((size_t)g0 * 4 + 3) * D4];
    float4 b0 = w4p[((size_t)(g0 + 1) * 4 + 0) * D4];
    float4 b1 = w4p[((size_t)(g0 + 1) * 4 + 1) * D4];
    float4 b2 = w4p[((size_t)(g0 + 1) * 4 + 2) * D4];
    float4 b3 = w4p[((size_t)(g0 + 1) * 4 + 3) * D4];

    int g = g0;
    for (; g + 3 < g1; g += 2) {
        // ---- compute with A (row g) ----
        const float4* __restrict__ f0 = fT4 + (size_t)g * BB;   // wave-uniform
#pragma unroll
        for (int b = 0; b < BB; ++b) {
            float4 fv = f0[b];
            FMA4(acc[b], a0, fv.x);
            FMA4(acc[b], a1, fv.y);
            FMA4(acc[b], a2, fv.z);
            FMA4(acc[b], a3, fv.w);
        }
        // refill A <- row g+2 (in flight across the B-compute ~1100 cy + next A-compute)
        a0 = w4p[((size_t)(g + 2) * 4 + 0) * D4];
        a1 = w4p[((size_t)(g + 2) * 4 + 1) * D4];
        a2 = w4p[((size_t)(g + 2) * 4 + 2) * D4];
        a3 = w4p[((size_t)(g + 2) * 4 + 3) * D4];

        // ---- compute with B (row g+1) ----
        const float4* __restrict__ f1 = f0 + BB;
#pragma unroll
        for (int b = 0; b < BB; ++b) {
            float4 fv = f1[b];
            FMA4(acc[b], b0, fv.x);
            FMA4(acc[b], b1, fv.y);
            FMA4(acc[b], b2, fv.z);
            FMA4(acc[b], b3, fv.w);
        }
        // refill B <- row g+3
        b0 = w4p[((size_t)(g + 3) * 4 + 0) * D4];
        b1 = w4p[((size_t)(g + 3) * 4 + 1) * D4];
        b2 = w4p[((size_t)(g + 3) * 4 + 2) * D4];
        b3 = w4p[((size_t)(g + 3) * 4 + 3) * D4];
    }

    // tail: exactly two rows g, g+1 held in A and B
    {
        const float4* __restrict__ f0 = fT4 + (size_t)g * BB;
#pragma unroll
        for (int b = 0; b < BB; ++b) {
            float4 fv = f0[b];
            FMA4(acc[b], a0, fv.x);
            FMA4(acc[b], a1, fv.y);
            FMA4(acc[b], a2, fv.z);
            FMA4(acc[b], a3, fv.w);
        }
        const float4* __restrict__ f1 = f0 + BB;
#pragma unroll
        for (int b = 0; b < BB; ++b) {
            float4 fv = f1[b];
            FMA4(acc[b], b0, fv.x);
            FMA4(acc[b], b1, fv.y);
            FMA4(acc[b], b2, fv.z);
            FMA4(acc[b], b3, fv.w);
        }
    }

    float4* __restrict__ out4 =
        (float4*)partials + (size_t)c * BB * LD4 + (size_t)(l * 192 + dt * 64 + lane);
#pragma unroll
    for (int b = 0; b < BB; ++b)
        out4[(size_t)b * LD4] = acc[b];
}

// Stage 2: out[b, ld] = bias[ld] + sum_c partials[c][b][ld]
__global__ __launch_bounds__(256) void cc_stage2(
    const float* __restrict__ partials,
    const float* __restrict__ bias,
    float* __restrict__ out,
    int nf)
{
    int o = blockIdx.x * 256 + threadIdx.x;   // 0 .. B*LD-1
    if (o >= BB * LD) return;
    int b  = o / LD;
    int ld = o - b * LD;
    float s = bias[ld];
    const float* __restrict__ p = partials + (size_t)b * LD + ld;
#pragma unroll 16
    for (int c = 0; c < nf; ++c)
        s += p[(size_t)c * (BB * LD)];
    out[o] = s;
}

// Correctness-only fallback if workspace is too small.
__global__ __launch_bounds__(256) void cc_direct(
    const float* __restrict__ f,
    const float* __restrict__ weight,
    const float* __restrict__ bias,
    float* __restrict__ out)
{
    int o = blockIdx.x * 256 + threadIdx.x;
    if (o >= BB * LD) return;
    int b  = o / LD;
    int ld = o - b * LD;
    int l  = ld / DD;
    int d  = ld - l * DD;
    float s = bias[ld];
    const float* wp = weight + (size_t)l * FF * DD + d;
    const float* fp = f + (size_t)b * FF;
    for (int fi = 0; fi < FF; ++fi)
        s = fmaf(fp[fi], wp[(size_t)fi * DD], s);
    out[o] = s;
}

extern "C" void kernel_launch(void* const* d_in, const int* in_sizes, int n_in,
                              void* d_out, int out_size, void* d_ws, size_t ws_size,
                              hipStream_t stream)
{
    const float* f      = (const float*)d_in[0];   // 32 x 65536
    const float* weight = (const float*)d_in[1];   // 2 x 65536 x 768
    const float* bias   = (const float*)d_in[2];   // 2 x 768
    float* out          = (float*)d_out;           // 32 x 2 x 768

    if (ws_size < FT_BYTES + CHUNK_BYTES) {
        cc_direct<<<(BB * LD + 255) / 256, 256, 0, stream>>>(f, weight, bias, out);
        return;
    }

    int nf = (int)((ws_size - FT_BYTES) / CHUNK_BYTES);
    if (nf > 256) nf = 256;
    // even chunk size so the 2x-unrolled pipeline has a clean 2-row tail
    int chunk4 = (F4 + nf - 1) / nf;
    chunk4 = (chunk4 + 1) & ~1;
    if (chunk4 < 2) chunk4 = 2;
    nf = (F4 + chunk4 - 1) / chunk4;

    float4* fT4      = (float4*)d_ws;
    float*  partials = (float*)((char*)d_ws + FT_BYTES);

    cc_transpose<<<(int)((FT_FLOAT4S + 255) / 256), 256, 0, stream>>>(
        (const float4*)f, fT4);

    dim3 grid1(6, nf);
    cc_stage1<<<grid1, 64, 0, stream>>>(fT4, weight, partials, chunk4);

    cc_stage2<<<(BB * LD + 255) / 256, 256, 0, stream>>>(
        partials, bias, out, nf);
}

// Round 7
// 155.786 us; speedup vs baseline: 2.3597x; 2.3597x over previous
//
#include <hip/hip_runtime.h>

// Problem constants: B=32, L=2, F=65536, D=768
#define BB 32
#define LL 2
#define FF 65536
#define DD 768
#define F4 (FF / 4)        // 16384 groups of 4 f
#define LD (LL * DD)       // 1536
#define LD2 (LD / 2)       // 768 float2
#define D2 (DD / 2)        // 384 float2 per weight row

#define FT_FLOAT4S ((size_t)F4 * BB)            // 524288 float4 = 8.39 MB
#define FT_BYTES   (FT_FLOAT4S * sizeof(float4))
#define CHUNK_BYTES ((size_t)BB * LD * sizeof(float))  // 196608 B

#define FMA2(A, W, S)                                                          \
    do {                                                                       \
        (A).x = fmaf((W).x, (S), (A).x);                                       \
        (A).y = fmaf((W).y, (S), (A).y);                                       \
    } while (0)

// Stage 0: transpose f (B x F) -> fT[g][b] as float4.
__global__ __launch_bounds__(256) void cc_transpose(
    const float4* __restrict__ f4, float4* __restrict__ fT4)
{
    size_t t = (size_t)blockIdx.x * 256 + threadIdx.x;   // 0 .. F4*32-1
    if (t >= FT_FLOAT4S) return;
    int b = (int)(t / F4);
    int g = (int)(t - (size_t)b * F4);
    fT4[(size_t)g * BB + b] = f4[t];
}

// Stage 1: partial GEMM over an F-chunk. float2-per-lane d-tiles of 128.
// grid = (12, NF); block = 64 (one wave).  ct: l = ct/6, dt = ct%6.
// partials[c][b][l*768 + dt*128 + lane*2]
// Depth-1 weight prefetch (R5-proven). VGPR demand ~95; capped at 128 via
// __launch_bounds__(64,4) so 4 waves/SIMD are guaranteed and spills impossible
// at this demand.
__global__ __launch_bounds__(64, 4) void cc_stage1(
    const float4* __restrict__ fT4,     // [F4][32] float4
    const float* __restrict__ weight,   // L x F x D
    float* __restrict__ partials,       // NF x B x LD
    int chunk4)
{
    const int lane = threadIdx.x;
    const int ct   = blockIdx.x;        // 0..11
    const int c    = blockIdx.y;        // chunk
    const int l    = ct / 6;
    const int dt   = ct - l * 6;

    const float2* __restrict__ w2p =
        (const float2*)weight + (size_t)l * FF * D2 + (size_t)dt * 64 + lane;

    int g0 = c * chunk4;
    int g1 = g0 + chunk4;
    if (g1 > F4) g1 = F4;

    float2 acc[BB];
#pragma unroll
    for (int b = 0; b < BB; ++b) acc[b] = make_float2(0.f, 0.f);

    // depth-1 prefetch of the 4 weight rows of group g0
    float2 w0 = w2p[((size_t)g0 * 4 + 0) * D2];
    float2 w1 = w2p[((size_t)g0 * 4 + 1) * D2];
    float2 w2 = w2p[((size_t)g0 * 4 + 2) * D2];
    float2 w3 = w2p[((size_t)g0 * 4 + 3) * D2];

    for (int g = g0; g < g1; ++g) {
        int gn = (g + 1 < g1) ? (g + 1) : g;   // clamp: last iter reloads, harmless
        float2 n0 = w2p[((size_t)gn * 4 + 0) * D2];
        float2 n1 = w2p[((size_t)gn * 4 + 1) * D2];
        float2 n2 = w2p[((size_t)gn * 4 + 2) * D2];
        float2 n3 = w2p[((size_t)gn * 4 + 3) * D2];

        const float4* __restrict__ fr = fT4 + (size_t)g * BB;  // wave-uniform, 512B
#pragma unroll
        for (int b = 0; b < BB; ++b) {
            float4 fv = fr[b];
            FMA2(acc[b], w0, fv.x);
            FMA2(acc[b], w1, fv.y);
            FMA2(acc[b], w2, fv.z);
            FMA2(acc[b], w3, fv.w);
        }
        w0 = n0; w1 = n1; w2 = n2; w3 = n3;
    }

    float2* __restrict__ out2 =
        (float2*)partials + (size_t)c * BB * LD2 + (size_t)(l * 384 + dt * 64 + lane);
#pragma unroll
    for (int b = 0; b < BB; ++b)
        out2[(size_t)b * LD2] = acc[b];
}

// Stage 2: out[b, ld] = bias[ld] + sum_c partials[c][b][ld]
__global__ __launch_bounds__(256) void cc_stage2(
    const float* __restrict__ partials,
    const float* __restrict__ bias,
    float* __restrict__ out,
    int nf)
{
    int o = blockIdx.x * 256 + threadIdx.x;   // 0 .. B*LD-1
    if (o >= BB * LD) return;
    int b  = o / LD;
    int ld = o - b * LD;
    float s = bias[ld];
    const float* __restrict__ p = partials + (size_t)b * LD + ld;
#pragma unroll 16
    for (int c = 0; c < nf; ++c)
        s += p[(size_t)c * (BB * LD)];
    out[o] = s;
}

// Correctness-only fallback if workspace is too small.
__global__ __launch_bounds__(256) void cc_direct(
    const float* __restrict__ f,
    const float* __restrict__ weight,
    const float* __restrict__ bias,
    float* __restrict__ out)
{
    int o = blockIdx.x * 256 + threadIdx.x;
    if (o >= BB * LD) return;
    int b  = o / LD;
    int ld = o - b * LD;
    int l  = ld / DD;
    int d  = ld - l * DD;
    float s = bias[ld];
    const float* wp = weight + (size_t)l * FF * DD + d;
    const float* fp = f + (size_t)b * FF;
    for (int fi = 0; fi < FF; ++fi)
        s = fmaf(fp[fi], wp[(size_t)fi * DD], s);
    out[o] = s;
}

extern "C" void kernel_launch(void* const* d_in, const int* in_sizes, int n_in,
                              void* d_out, int out_size, void* d_ws, size_t ws_size,
                              hipStream_t stream)
{
    const float* f      = (const float*)d_in[0];   // 32 x 65536
    const float* weight = (const float*)d_in[1];   // 2 x 65536 x 768
    const float* bias   = (const float*)d_in[2];   // 2 x 768
    float* out          = (float*)d_out;           // 32 x 2 x 768

    if (ws_size < FT_BYTES + CHUNK_BYTES) {
        cc_direct<<<(BB * LD + 255) / 256, 256, 0, stream>>>(f, weight, bias, out);
        return;
    }

    int nf = (int)((ws_size - FT_BYTES) / CHUNK_BYTES);
    if (nf > 256) nf = 256;
    int chunk4 = (F4 + nf - 1) / nf;        // 64 when nf=256
    nf = (F4 + chunk4 - 1) / chunk4;

    float4* fT4      = (float4*)d_ws;
    float*  partials = (float*)((char*)d_ws + FT_BYTES);

    cc_transpose<<<(int)((FT_FLOAT4S + 255) / 256), 256, 0, stream>>>(
        (const float4*)f, fT4);

    dim3 grid1(12, nf);
    cc_stage1<<<grid1, 64, 0, stream>>>(fT4, weight, partials, chunk4);

    cc_stage2<<<(BB * LD + 255) / 256, 256, 0, stream>>>(
        partials, bias, out, nf);
}